// Round 2
// baseline (607.064 us; speedup 1.0000x reference)
//
#include <hip/hip_runtime.h>
#include <math.h>

#define NNODES 50000
#define NEDGES 800000
#define NGRAPHS 500
#define NEG_SLOPE 0.2f
#define BN_EPS 1e-5f
#define NRANGE 196            // ceil(50000/256) node ranges of 256
#define RH_EPB 4096           // edges per block in range hist/reorder
#define RH_NB ((NEDGES + RH_EPB - 1) / RH_EPB)
#define MAXRE 5120            // LDS stage capacity per range
#define BN_NB 200
#define BN_RPB 250

typedef unsigned int uint;
typedef unsigned short ushort;
typedef __attribute__((ext_vector_type(8))) short bf16x8;
typedef __attribute__((ext_vector_type(4))) float f32x4;

// ---- bf16 helpers (storage-only bf16; math fp32 / MFMA fp32-acc) ----
__device__ __forceinline__ float bf2f(ushort u) { return __uint_as_float(((uint)u) << 16); }
__device__ __forceinline__ float bflo(uint u)   { return __uint_as_float(u << 16); }
__device__ __forceinline__ float bfhi(uint u)   { return __uint_as_float(u & 0xffff0000u); }
__device__ __forceinline__ ushort f2bf(float f) {
    uint u = __float_as_uint(f);
    u = (u + 0x7fffu + ((u >> 16) & 1u)) >> 16;   // RNE
    return (ushort)u;
}

// agent-scope (device) coherent load/store — dodge stale per-XCD L2 lines
__device__ __forceinline__ float ld_dev(const float* p) {
    return __hip_atomic_load(p, __ATOMIC_RELAXED, __HIP_MEMORY_SCOPE_AGENT);
}
__device__ __forceinline__ void st_dev(float* p, float v) {
    __hip_atomic_store(p, v, __ATOMIC_RELAXED, __HIP_MEMORY_SCOPE_AGENT);
}

// ---- prep (weight convert/transpose) FUSED with range histogram ----
// rhist zeroed by the single hipMemsetAsync before this launch.
__global__ __launch_bounds__(256) void prep_hist_kernel(
        const float* __restrict__ W0, const float* __restrict__ W1,
        const float* __restrict__ W2, ushort* __restrict__ Wt0,
        ushort* __restrict__ Wt1, ushort* __restrict__ Wt2,
        const int* __restrict__ dst, int* __restrict__ rhist,
        int* __restrict__ rowptr) {
    int t = blockIdx.x * 256 + threadIdx.x;
    if (t == 0) rowptr[NNODES] = NEDGES;
    if (t < 16384) {                       // W0 [128][128]
        int k = t >> 7, m = t & 127;
        Wt0[m * 128 + k] = f2bf(W0[t]);
    } else if (t < 32768) {                // W1 [128][128]
        int i = t - 16384;
        int k = i >> 7, m = i & 127;
        Wt1[m * 128 + k] = f2bf(W1[i]);
    } else if (t < 36864) {                // W2 [128][32]
        int i = t - 32768;
        int k = i >> 5, m = i & 31;
        Wt2[m * 128 + k] = f2bf(W2[i]);
    }
    // range histogram over this block's edge slice
    __shared__ int cnt[NRANGE];
    for (int i = threadIdx.x; i < NRANGE; i += 256) cnt[i] = 0;
    __syncthreads();
    int base = blockIdx.x * RH_EPB;
    int end = base + RH_EPB; if (end > NEDGES) end = NEDGES;
    for (int i = base + threadIdx.x; i < end; i += 256) atomicAdd(&cnt[dst[i] >> 8], 1);
    __syncthreads();
    for (int i = threadIdx.x; i < NRANGE; i += 256)
        if (cnt[i]) atomicAdd(&rhist[i], cnt[i]);
}

// ==================== bucketed CSR build (scan fused redundantly per block) ====================
__global__ __launch_bounds__(256) void reorder_kernel(
        const int* __restrict__ src, const int* __restrict__ dst,
        const int* __restrict__ rhist, int* __restrict__ rcursor,
        uint* __restrict__ bucket) {
    __shared__ int cnt[NRANGE];
    __shared__ int bofs[NRANGE];
    __shared__ int rb[256];            // inclusive scan of rhist
    const int t = threadIdx.x;
    rb[t] = (t < NRANGE) ? rhist[t] : 0;
    cnt[t < NRANGE ? t : 0] = 0;       // NRANGE<=256: one pass
    if (t < NRANGE) cnt[t] = 0;
    __syncthreads();
    for (int off = 1; off < 256; off <<= 1) {
        int u = (t >= off) ? rb[t - off] : 0;
        __syncthreads();
        rb[t] += u;
        __syncthreads();
    }
    int base = blockIdx.x * RH_EPB;
    int end = base + RH_EPB; if (end > NEDGES) end = NEDGES;
    for (int i = base + t; i < end; i += 256) atomicAdd(&cnt[dst[i] >> 8], 1);
    __syncthreads();
    for (int i = t; i < NRANGE; i += 256) {
        int c = cnt[i];
        int ex = (i == 0) ? 0 : rb[i - 1];           // exclusive range base
        bofs[i] = c ? (ex + atomicAdd(&rcursor[i], c)) : 0;
    }
    __syncthreads();
    for (int i = t; i < NRANGE; i += 256) cnt[i] = 0;
    __syncthreads();
    for (int i = base + t; i < end; i += 256) {
        int d = dst[i], r = d >> 8;
        int loc = atomicAdd(&cnt[r], 1);
        bucket[bofs[r] + loc] = (uint)src[i] | ((uint)(d & 255) << 16);
    }
}

__global__ __launch_bounds__(256) void range_csr_kernel(const int* __restrict__ rhist,
                                                        const uint* __restrict__ bucket,
                                                        int* __restrict__ rowptr,
                                                        int* __restrict__ csr_src) {
    __shared__ uint ebuf[MAXRE];
    __shared__ int deg[256], excl[256], cur[256];
    __shared__ int rb[256];
    const int r = blockIdx.x;
    const int t = threadIdx.x;
    rb[t] = (t < NRANGE) ? rhist[t] : 0;
    __syncthreads();
    for (int off = 1; off < 256; off <<= 1) {
        int u = (t >= off) ? rb[t - off] : 0;
        __syncthreads();
        rb[t] += u;
        __syncthreads();
    }
    const int b0 = (r == 0) ? 0 : rb[r - 1];
    const int cnt = rb[r] - b0;
    deg[t] = 0; cur[t] = 0;
    __syncthreads();
    for (int i = t; i < cnt; i += 256) {
        uint e = bucket[b0 + i];
        ebuf[i] = e;
        atomicAdd(&deg[e >> 16], 1);
    }
    __syncthreads();
    excl[t] = deg[t];
    __syncthreads();
    for (int off = 1; off < 256; off <<= 1) {
        int u = (t >= off) ? excl[t - off] : 0;
        __syncthreads();
        excl[t] += u;
        __syncthreads();
    }
    int myExcl = (t == 0) ? 0 : excl[t - 1];
    __syncthreads();
    excl[t] = myExcl;
    __syncthreads();
    int node = r * 256 + t;
    if (node < NNODES) rowptr[node] = b0 + myExcl;
    for (int i = t; i < cnt; i += 256) {
        uint e = ebuf[i];
        int dl = e >> 16;
        int loc = atomicAdd(&cur[dl], 1);
        csr_src[b0 + excl[dl] + loc] = (int)(e & 0xffffu);
    }
}

// ==================== MFMA bf16 GEMM, fused BN/ReLU input + el/er epilogue ====================
// HASBN: X bf16, scale/shift precomputed. !HASBN: X fp32.
template <int M, bool HASBN>
__global__ __launch_bounds__(256) void gemm_mfma_kernel(
        const void* __restrict__ Xv, const ushort* __restrict__ Wt,
        const float* __restrict__ scale, const float* __restrict__ shift,
        const float* __restrict__ al, const float* __restrict__ ar,
        ushort* __restrict__ Y, float* __restrict__ el, float* __restrict__ er, int N) {
    constexpr int H   = M / 32;
    constexpr int BR  = (M == 128) ? 64 : 128;
    constexpr int RT  = (M == 128) ? 4 : 2;
    constexpr int CT  = 2;
    constexpr int LDK = 136;
    __shared__ ushort xs[BR][LDK];
    __shared__ ushort ws[M][LDK];
    __shared__ float scs[128], shs[128];

    const int tid = threadIdx.x, wv = tid >> 6, lane = tid & 63;
    const int rowBase = blockIdx.x * BR;

    if (HASBN) {
        if (tid < 128) {
            scs[tid] = scale[tid];
            shs[tid] = shift[tid];
        }
        __syncthreads();
    }

    if (HASBN) {
        const ushort* X = (const ushort*)Xv;
        for (int i = tid; i < BR * 16; i += 256) {
            int rr = i >> 4, q = i & 15;
            int gr = rowBase + rr;
            uint4 u = make_uint4(0, 0, 0, 0);
            if (gr < N) u = *(const uint4*)(X + (size_t)gr * 128 + q * 8);
            uint arr[4] = {u.x, u.y, u.z, u.w};
            ushort* o = &xs[rr][q * 8];
#pragma unroll
            for (int j = 0; j < 4; ++j) {
                int c = q * 8 + j * 2;
                float lo = fmaxf(bflo(arr[j]) * scs[c] + shs[c], 0.f);
                float hi = fmaxf(bfhi(arr[j]) * scs[c + 1] + shs[c + 1], 0.f);
                o[j * 2]     = f2bf(lo);
                o[j * 2 + 1] = f2bf(hi);
            }
        }
    } else {
        const float* X = (const float*)Xv;
        for (int i = tid; i < BR * 32; i += 256) {
            int rr = i >> 5, c4 = i & 31;
            int gr = rowBase + rr;
            float4 v = make_float4(0.f, 0.f, 0.f, 0.f);
            if (gr < N) v = *(const float4*)(X + (size_t)gr * 128 + c4 * 4);
            ushort* o = &xs[rr][c4 * 4];
            o[0] = f2bf(v.x); o[1] = f2bf(v.y); o[2] = f2bf(v.z); o[3] = f2bf(v.w);
        }
    }
    for (int i = tid; i < M * 16; i += 256) {
        int rr = i >> 4, kc = (i & 15) * 8;
        *(uint4*)&ws[rr][kc] = *(const uint4*)(Wt + rr * 128 + kc);
    }
    __syncthreads();

    const int waveRow = (M == 128) ? 0 : (wv * 32);
    const int waveCol = (M == 128) ? (wv * 32) : 0;
    const int fr = lane & 15, quad = lane >> 4;

    f32x4 acc[RT][CT];
#pragma unroll
    for (int rt = 0; rt < RT; ++rt)
#pragma unroll
        for (int ct = 0; ct < CT; ++ct) acc[rt][ct] = (f32x4){0.f, 0.f, 0.f, 0.f};

#pragma unroll
    for (int ks = 0; ks < 4; ++ks) {
        const int kb = ks * 32 + quad * 8;
        bf16x8 a[RT], b[CT];
#pragma unroll
        for (int rt = 0; rt < RT; ++rt) a[rt] = *(const bf16x8*)&xs[waveRow + rt * 16 + fr][kb];
#pragma unroll
        for (int ct = 0; ct < CT; ++ct) b[ct] = *(const bf16x8*)&ws[waveCol + ct * 16 + fr][kb];
#pragma unroll
        for (int rt = 0; rt < RT; ++rt)
#pragma unroll
            for (int ct = 0; ct < CT; ++ct)
                acc[rt][ct] = __builtin_amdgcn_mfma_f32_16x16x32_bf16(a[rt], b[ct], acc[rt][ct], 0, 0, 0);
    }

#pragma unroll
    for (int rt = 0; rt < RT; ++rt)
#pragma unroll
        for (int ct = 0; ct < CT; ++ct)
#pragma unroll
            for (int rg = 0; rg < 4; ++rg) {
                int gr = rowBase + waveRow + rt * 16 + quad * 4 + rg;
                int gc = waveCol + ct * 16 + fr;
                if (gr < N) Y[(size_t)gr * M + gc] = f2bf(acc[rt][ct][rg]);
            }

    // fused el/er epilogue
    const float a0 = al[waveCol + fr],      a1 = al[waveCol + 16 + fr];
    const float g0 = ar[waveCol + fr],      g1 = ar[waveCol + 16 + fr];
    const int h = (M == 128) ? wv : 0;
#pragma unroll
    for (int rt = 0; rt < RT; ++rt)
#pragma unroll
        for (int rg = 0; rg < 4; ++rg) {
            float pe = acc[rt][0][rg] * a0 + acc[rt][1][rg] * a1;
            float pr = acc[rt][0][rg] * g0 + acc[rt][1][rg] * g1;
#pragma unroll
            for (int off = 1; off < 16; off <<= 1) {
                pe += __shfl_xor(pe, off);
                pr += __shfl_xor(pr, off);
            }
            int grow = rowBase + waveRow + rt * 16 + quad * 4 + rg;
            if (fr == 0 && grow < N) {
                el[grow * H + h] = pe;
                er[grow * H + h] = pr;
            }
        }
}

// ==================== gather H=4: one node/wave, bf16 out — NO atomics, NO LDS ====================
// grid is EXACT (12500 blocks * 4 waves = 50000 nodes): no early-return waves.
__global__ __launch_bounds__(256) void gat_gather4_kernel(
        const int* __restrict__ rowptr, const int* __restrict__ csr_src,
        const float* __restrict__ el, const float* __restrict__ er,
        const ushort* __restrict__ feat, const float* __restrict__ bias,
        ushort* __restrict__ xnext) {
    const int d = __builtin_amdgcn_readfirstlane(
        (int)((blockIdx.x * blockDim.x + threadIdx.x) >> 6));
    const int lane = threadIdx.x & 63;
    if (d >= NNODES) return;
    const int h   = lane >> 4;
    const int k   = lane & 15;
    const int grp = lane & 48;
    const int c0  = lane * 2;
    const int r0 = rowptr[d];
    const int deg = rowptr[d + 1] - r0;
    const float erh = er[d * 4 + h];
    float dnm = 0.f, ax = 0.f, ay = 0.f;

    for (int j0 = 0; j0 < deg; j0 += 16) {
        int eidx = j0 + k;
        int s_e = 0;
        float ex = 0.f;
        if (eidx < deg) {
            s_e = csr_src[r0 + eidx];
            float v = el[s_e * 4 + h] + erh;
            v = v > 0.f ? v : NEG_SLOPE * v;
            ex = __expf(v);
        }
        dnm += ex;
        uint u[16];
#pragma unroll
        for (int jj = 0; jj < 16; ++jj) {
            int sj = __builtin_amdgcn_readlane(s_e, jj);
            u[jj] = *(const uint*)(feat + (size_t)sj * 128 + c0);
        }
#pragma unroll
        for (int jj = 0; jj < 16; ++jj) {
            float exj = __shfl(ex, grp + jj);
            ax = fmaf(exj, bflo(u[jj]), ax);
            ay = fmaf(exj, bfhi(u[jj]), ay);
        }
    }
#pragma unroll
    for (int off = 1; off < 16; off <<= 1) dnm += __shfl_xor(dnm, off);
    float inv = (dnm > 0.f) ? 1.f / dnm : 0.f;
    float vx = ax * inv + bias[c0];
    float vy = ay * inv + bias[c0 + 1];
    uint pk = ((uint)f2bf(vy) << 16) | (uint)f2bf(vx);
    *(uint*)(xnext + (size_t)d * 128 + c0) = pk;
}

// ---- BN stats + FUSED finalize (last-block-done) ----
__global__ __launch_bounds__(256) void bn_stats_kernel(
        const ushort* __restrict__ X, float* __restrict__ psum, float* __restrict__ psumsq,
        const float* __restrict__ g, const float* __restrict__ beta,
        float* __restrict__ scale, float* __restrict__ shift, int* __restrict__ counter) {
    const uint* X32 = (const uint*)X;          // [N][64] packed col pairs
    int uc = threadIdx.x & 63;                 // uint col (cols 2uc, 2uc+1)
    int rq = threadIdx.x >> 6;                 // row quarter
    int r0 = blockIdx.x * BN_RPB;
    float s0 = 0.f, s1 = 0.f, ss0 = 0.f, ss1 = 0.f;
    for (int r = r0 + rq; r < r0 + BN_RPB; r += 4) {
        uint u = X32[(size_t)r * 64 + uc];
        float lo = bflo(u), hi = bfhi(u);
        s0 += lo; ss0 += lo * lo;
        s1 += hi; ss1 += hi * hi;
    }
    __shared__ float red[4][256], redsq[4][256];
    red[rq][uc * 2] = s0;      red[rq][uc * 2 + 1] = s1;
    redsq[rq][uc * 2] = ss0;   redsq[rq][uc * 2 + 1] = ss1;
    __syncthreads();
    int t = threadIdx.x;
    if (t < 128) {
        st_dev(&psum[blockIdx.x * 128 + t], red[0][t] + red[1][t] + red[2][t] + red[3][t]);
    } else {
        int c = t - 128;
        st_dev(&psumsq[blockIdx.x * 128 + c], redsq[0][c] + redsq[1][c] + redsq[2][c] + redsq[3][c]);
    }
    // last-block finalize. __syncthreads drains all waves' stores (vmcnt(0) before barrier).
    __syncthreads();
    __shared__ int isLast;
    if (t == 0) {
        __threadfence();
        isLast = (atomicAdd(counter, 1) == (int)gridDim.x - 1);
    }
    __syncthreads();
    if (!isLast) return;
    __threadfence();
    if (t < 128) {
        float s = 0.f, ss = 0.f;
        for (int b = 0; b < BN_NB; ++b) {
            s += ld_dev(&psum[b * 128 + t]);
            ss += ld_dev(&psumsq[b * 128 + t]);
        }
        const float inv = 1.f / NNODES;
        float mu = s * inv;
        float var = ss * inv - mu * mu;
        float sc = g[t] * rsqrtf(var + BN_EPS);
        scale[t] = sc;
        shift[t] = beta[t] - mu * sc;
    }
}

// ==================== gather H=1 + graph pooling + FUSED classifier ====================
// grid is EXACT (12500 blocks): every block reaches the counter bump.
__global__ __launch_bounds__(256) void gat_gather1_kernel(
        const int* __restrict__ rowptr, const int* __restrict__ csr_src,
        const float* __restrict__ el, const float* __restrict__ er,
        const ushort* __restrict__ feat, const float* __restrict__ bias,
        const int* __restrict__ gid, float* __restrict__ pooled,
        const float* __restrict__ Wc, const float* __restrict__ bc,
        float* __restrict__ out, int* __restrict__ counter) {
    const int d = __builtin_amdgcn_readfirstlane(
        (int)((blockIdx.x * blockDim.x + threadIdx.x) >> 6));
    int lane = threadIdx.x & 63;
    const int r0 = rowptr[d];
    const int deg = rowptr[d + 1] - r0;
    const int half = lane >> 5;
    const int c    = lane & 31;
    const float erh = er[d];
    float dnm = 0.f, acc = 0.f;

    for (int j0 = 0; j0 < deg; j0 += 32) {
        int eidx = j0 + (lane & 31);
        int s_e = 0;
        float ex = 0.f;
        if (eidx < deg) {
            s_e = csr_src[r0 + eidx];
            float v = el[s_e] + erh;
            v = v > 0.f ? v : NEG_SLOPE * v;
            ex = __expf(v);
        }
        dnm += ex;
        ushort u[16];
#pragma unroll
        for (int jj = 0; jj < 16; ++jj) {
            int sj = __shfl(s_e, 2 * jj + half);
            u[jj] = feat[(size_t)sj * 32 + c];
        }
#pragma unroll
        for (int jj = 0; jj < 16; ++jj) {
            float exj = __shfl(ex, 2 * jj + half);
            acc = fmaf(exj, bf2f(u[jj]), acc);
        }
    }
#pragma unroll
    for (int off = 1; off < 32; off <<= 1) dnm += __shfl_xor(dnm, off);
    acc += __shfl_down(acc, 32);
    if (half == 0) {
        float inv = (dnm > 0.f) ? 1.f / dnm : 0.f;
        atomicAdd(&pooled[gid[d] * 32 + c], acc * inv + bias[c]);
    }
    // last-block classifier. __syncthreads drains all waves' atomics first.
    __syncthreads();
    __shared__ int isLast;
    if (threadIdx.x == 0) {
        __threadfence();
        isLast = (atomicAdd(counter, 1) == (int)gridDim.x - 1);
    }
    __syncthreads();
    if (!isLast) return;
    __threadfence();
    for (int g = threadIdx.x; g < NGRAPHS; g += 256) {
        float pv[32];
#pragma unroll
        for (int cc = 0; cc < 32; ++cc) pv[cc] = ld_dev(&pooled[g * 32 + cc]);
#pragma unroll
        for (int j = 0; j < 10; ++j) {
            float s = bc[j];
#pragma unroll
            for (int cc = 0; cc < 32; ++cc) s = fmaf(pv[cc], Wc[cc * 10 + j], s);
            out[g * 10 + j] = s;
        }
    }
}

extern "C" void kernel_launch(void* const* d_in, const int* in_sizes, int n_in,
                              void* d_out, int out_size, void* d_ws, size_t ws_size,
                              hipStream_t stream) {
    const float* x     = (const float*)d_in[0];
    const int*   esrc  = (const int*)d_in[1];
    const int*   edst  = (const int*)d_in[2];
    const int*   gid   = (const int*)d_in[3];
    const float* W0    = (const float*)d_in[4];
    const float* al0   = (const float*)d_in[5];
    const float* ar0   = (const float*)d_in[6];
    const float* b0    = (const float*)d_in[7];
    const float* W1    = (const float*)d_in[8];
    const float* al1   = (const float*)d_in[9];
    const float* ar1   = (const float*)d_in[10];
    const float* b1    = (const float*)d_in[11];
    const float* W2    = (const float*)d_in[12];
    const float* al2   = (const float*)d_in[13];
    const float* ar2   = (const float*)d_in[14];
    const float* b2    = (const float*)d_in[15];
    const float* g0    = (const float*)d_in[16];
    const float* beta0 = (const float*)d_in[17];
    const float* g1    = (const float*)d_in[18];
    const float* beta1 = (const float*)d_in[19];
    const float* Wc    = (const float*)d_in[20];
    const float* bc    = (const float*)d_in[21];

    // ---- workspace layout: one contiguous zero-init region first ----
    int*   counters = (int*)d_ws;                             // [8]: 0=bn0 1=bn1 2=pool
    int*   rhist    = counters + 8;                           // [196]
    int*   rcursor  = rhist + NRANGE;                         // [196]
    float* pooled   = (float*)(rcursor + NRANGE);             // [500*32]
    // zero region ends here: (8+196+196+16000)*4 bytes
    float* psum     = pooled + NGRAPHS * 32;                  // [200*128]
    float* psumsq   = psum + BN_NB * 128;                     // [200*128]
    float* scale0   = psumsq + BN_NB * 128;                   // [128]
    float* shift0   = scale0 + 128;
    float* scale1   = shift0 + 128;
    float* shift1   = scale1 + 128;
    int*   rowptr   = (int*)(shift1 + 128);                   // [N+1]
    int*   csr_src  = rowptr + NNODES + 1;                    // [E]
    uint*  bucket   = (uint*)(csr_src + NEDGES);              // [E]
    // pad to 16B alignment for the bf16 feature buffers
    size_t ofs = (size_t)((int*)(bucket + NEDGES) - (int*)d_ws);
    ofs = (ofs + 3) & ~(size_t)3;                             // round up to multiple of 4 ints
    ushort* featbf = (ushort*)((int*)d_ws + ofs);             // [N,128] bf16 GEMM out
    ushort* xnext  = featbf + (size_t)NNODES * 128;           // [N,128] bf16 gather out / GEMM in
    float*  el     = (float*)(xnext + (size_t)NNODES * 128);  // [N,4]
    float*  er     = el + (size_t)NNODES * 4;                 // [N,4]
    ushort* Wt0    = (ushort*)(er + (size_t)NNODES * 4);      // [128,128]
    ushort* Wt1    = Wt0 + 128 * 128;                         // [128,128]
    ushort* Wt2    = Wt1 + 128 * 128;                         // [32,128]

    const int T = 256;
    float* out = (float*)d_out;

    // ---- single zero-init (counters + rhist + rcursor + pooled) ----
    hipMemsetAsync(counters, 0, (size_t)(8 + NRANGE + NRANGE + NGRAPHS * 32) * 4, stream);
    prep_hist_kernel<<<RH_NB, T, 0, stream>>>(W0, W1, W2, Wt0, Wt1, Wt2, edst, rhist, rowptr);

    // ---- bucketed CSR build (scan folded into reorder/range_csr) ----
    reorder_kernel<<<RH_NB, T, 0, stream>>>(esrc, edst, rhist, rcursor, bucket);
    range_csr_kernel<<<NRANGE, T, 0, stream>>>(rhist, bucket, rowptr, csr_src);

    const int GATHER_BLOCKS  = (NNODES * 64) / T;             // exact: 12500
    const int GEMM128_BLOCKS = (NNODES + 63) / 64;
    const int GEMM32_BLOCKS  = (NNODES + 127) / 128;

    // ================= Layer 0 =================
    gemm_mfma_kernel<128, false><<<GEMM128_BLOCKS, T, 0, stream>>>(
        x, Wt0, nullptr, nullptr, al0, ar0, featbf, el, er, NNODES);
    gat_gather4_kernel<<<GATHER_BLOCKS, T, 0, stream>>>(rowptr, csr_src, el, er, featbf, b0, xnext);
    bn_stats_kernel<<<BN_NB, T, 0, stream>>>(xnext, psum, psumsq, g0, beta0, scale0, shift0,
                                             &counters[0]);

    // ================= Layer 1 =================
    gemm_mfma_kernel<128, true><<<GEMM128_BLOCKS, T, 0, stream>>>(
        xnext, Wt1, scale0, shift0, al1, ar1, featbf, el, er, NNODES);
    gat_gather4_kernel<<<GATHER_BLOCKS, T, 0, stream>>>(rowptr, csr_src, el, er, featbf, b1, xnext);
    bn_stats_kernel<<<BN_NB, T, 0, stream>>>(xnext, psum, psumsq, g1, beta1, scale1, shift1,
                                             &counters[1]);

    // ================= Layer 2 (H=1, D=32) + pooling + classify =================
    gemm_mfma_kernel<32, true><<<GEMM32_BLOCKS, T, 0, stream>>>(
        xnext, Wt2, scale1, shift1, al2, ar2, featbf, el, er, NNODES);
    gat_gather1_kernel<<<GATHER_BLOCKS, T, 0, stream>>>(rowptr, csr_src, el, er, featbf, b2,
                                                        gid, pooled, Wc, bc, out, &counters[2]);
}

// Round 3
// 358.360 us; speedup vs baseline: 1.6940x; 1.6940x over previous
//
#include <hip/hip_runtime.h>
#include <math.h>

#define NNODES 50000
#define NEDGES 800000
#define NGRAPHS 500
#define NEG_SLOPE 0.2f
#define BN_EPS 1e-5f
#define NRANGE 196            // ceil(50000/256) node ranges of 256
#define RH_EPB 4096           // edges per block in range hist/reorder
#define RH_NB ((NEDGES + RH_EPB - 1) / RH_EPB)
#define MAXRE 5120            // LDS stage capacity per range
#define BN_NB 200
#define BN_RPB 250

typedef unsigned int uint;
typedef unsigned short ushort;
typedef __attribute__((ext_vector_type(8))) short bf16x8;
typedef __attribute__((ext_vector_type(4))) float f32x4;

// ---- bf16 helpers (storage-only bf16; math fp32 / MFMA fp32-acc) ----
__device__ __forceinline__ float bf2f(ushort u) { return __uint_as_float(((uint)u) << 16); }
__device__ __forceinline__ float bflo(uint u)   { return __uint_as_float(u << 16); }
__device__ __forceinline__ float bfhi(uint u)   { return __uint_as_float(u & 0xffff0000u); }
__device__ __forceinline__ ushort f2bf(float f) {
    uint u = __float_as_uint(f);
    u = (u + 0x7fffu + ((u >> 16) & 1u)) >> 16;   // RNE
    return (ushort)u;
}

// agent-scope (device) coherent load/store — complete at the coherence point,
// visible cross-XCD without fences (per-XCD L2 is non-coherent for plain ops).
__device__ __forceinline__ float ld_dev(const float* p) {
    return __hip_atomic_load(p, __ATOMIC_RELAXED, __HIP_MEMORY_SCOPE_AGENT);
}
__device__ __forceinline__ void st_dev(float* p, float v) {
    __hip_atomic_store(p, v, __ATOMIC_RELAXED, __HIP_MEMORY_SCOPE_AGENT);
}

// ---- prep (weight convert/transpose) FUSED with range histogram ----
__global__ __launch_bounds__(256) void prep_hist_kernel(
        const float* __restrict__ W0, const float* __restrict__ W1,
        const float* __restrict__ W2, ushort* __restrict__ Wt0,
        ushort* __restrict__ Wt1, ushort* __restrict__ Wt2,
        const int* __restrict__ dst, int* __restrict__ rhist,
        int* __restrict__ rowptr) {
    int t = blockIdx.x * 256 + threadIdx.x;
    if (t == 0) rowptr[NNODES] = NEDGES;
    if (t < 16384) {                       // W0 [128][128]
        int k = t >> 7, m = t & 127;
        Wt0[m * 128 + k] = f2bf(W0[t]);
    } else if (t < 32768) {                // W1 [128][128]
        int i = t - 16384;
        int k = i >> 7, m = i & 127;
        Wt1[m * 128 + k] = f2bf(W1[i]);
    } else if (t < 36864) {                // W2 [128][32]
        int i = t - 32768;
        int k = i >> 5, m = i & 31;
        Wt2[m * 128 + k] = f2bf(W2[i]);
    }
    __shared__ int cnt[NRANGE];
    for (int i = threadIdx.x; i < NRANGE; i += 256) cnt[i] = 0;
    __syncthreads();
    int base = blockIdx.x * RH_EPB;
    int end = base + RH_EPB; if (end > NEDGES) end = NEDGES;
    for (int i = base + threadIdx.x; i < end; i += 256) atomicAdd(&cnt[dst[i] >> 8], 1);
    __syncthreads();
    for (int i = threadIdx.x; i < NRANGE; i += 256)
        if (cnt[i]) atomicAdd(&rhist[i], cnt[i]);
}

// ==================== bucketed CSR build (scan fused redundantly per block) ====================
__global__ __launch_bounds__(256) void reorder_kernel(
        const int* __restrict__ src, const int* __restrict__ dst,
        const int* __restrict__ rhist, int* __restrict__ rcursor,
        uint* __restrict__ bucket) {
    __shared__ int cnt[NRANGE];
    __shared__ int bofs[NRANGE];
    __shared__ int rb[256];            // inclusive scan of rhist
    const int t = threadIdx.x;
    rb[t] = (t < NRANGE) ? rhist[t] : 0;
    if (t < NRANGE) cnt[t] = 0;
    __syncthreads();
    for (int off = 1; off < 256; off <<= 1) {
        int u = (t >= off) ? rb[t - off] : 0;
        __syncthreads();
        rb[t] += u;
        __syncthreads();
    }
    int base = blockIdx.x * RH_EPB;
    int end = base + RH_EPB; if (end > NEDGES) end = NEDGES;
    for (int i = base + t; i < end; i += 256) atomicAdd(&cnt[dst[i] >> 8], 1);
    __syncthreads();
    for (int i = t; i < NRANGE; i += 256) {
        int c = cnt[i];
        int ex = (i == 0) ? 0 : rb[i - 1];           // exclusive range base
        bofs[i] = c ? (ex + atomicAdd(&rcursor[i], c)) : 0;
    }
    __syncthreads();
    for (int i = t; i < NRANGE; i += 256) cnt[i] = 0;
    __syncthreads();
    for (int i = base + t; i < end; i += 256) {
        int d = dst[i], r = d >> 8;
        int loc = atomicAdd(&cnt[r], 1);
        bucket[bofs[r] + loc] = (uint)src[i] | ((uint)(d & 255) << 16);
    }
}

__global__ __launch_bounds__(256) void range_csr_kernel(const int* __restrict__ rhist,
                                                        const uint* __restrict__ bucket,
                                                        int* __restrict__ rowptr,
                                                        int* __restrict__ csr_src) {
    __shared__ uint ebuf[MAXRE];
    __shared__ int deg[256], excl[256], cur[256];
    __shared__ int rb[256];
    const int r = blockIdx.x;
    const int t = threadIdx.x;
    rb[t] = (t < NRANGE) ? rhist[t] : 0;
    __syncthreads();
    for (int off = 1; off < 256; off <<= 1) {
        int u = (t >= off) ? rb[t - off] : 0;
        __syncthreads();
        rb[t] += u;
        __syncthreads();
    }
    const int b0 = (r == 0) ? 0 : rb[r - 1];
    const int cnt = rb[r] - b0;
    deg[t] = 0; cur[t] = 0;
    __syncthreads();
    for (int i = t; i < cnt; i += 256) {
        uint e = bucket[b0 + i];
        ebuf[i] = e;
        atomicAdd(&deg[e >> 16], 1);
    }
    __syncthreads();
    excl[t] = deg[t];
    __syncthreads();
    for (int off = 1; off < 256; off <<= 1) {
        int u = (t >= off) ? excl[t - off] : 0;
        __syncthreads();
        excl[t] += u;
        __syncthreads();
    }
    int myExcl = (t == 0) ? 0 : excl[t - 1];
    __syncthreads();
    excl[t] = myExcl;
    __syncthreads();
    int node = r * 256 + t;
    if (node < NNODES) rowptr[node] = b0 + myExcl;
    for (int i = t; i < cnt; i += 256) {
        uint e = ebuf[i];
        int dl = e >> 16;
        int loc = atomicAdd(&cur[dl], 1);
        csr_src[b0 + excl[dl] + loc] = (int)(e & 0xffffu);
    }
}

// ==================== MFMA bf16 GEMM, fused BN/ReLU input + el/er epilogue ====================
template <int M, bool HASBN>
__global__ __launch_bounds__(256) void gemm_mfma_kernel(
        const void* __restrict__ Xv, const ushort* __restrict__ Wt,
        const float* __restrict__ scale, const float* __restrict__ shift,
        const float* __restrict__ al, const float* __restrict__ ar,
        ushort* __restrict__ Y, float* __restrict__ el, float* __restrict__ er, int N) {
    constexpr int H   = M / 32;
    constexpr int BR  = (M == 128) ? 64 : 128;
    constexpr int RT  = (M == 128) ? 4 : 2;
    constexpr int CT  = 2;
    constexpr int LDK = 136;
    __shared__ ushort xs[BR][LDK];
    __shared__ ushort ws[M][LDK];
    __shared__ float scs[128], shs[128];

    const int tid = threadIdx.x, wv = tid >> 6, lane = tid & 63;
    const int rowBase = blockIdx.x * BR;

    if (HASBN) {
        if (tid < 128) {
            scs[tid] = scale[tid];
            shs[tid] = shift[tid];
        }
        __syncthreads();
    }

    if (HASBN) {
        const ushort* X = (const ushort*)Xv;
        for (int i = tid; i < BR * 16; i += 256) {
            int rr = i >> 4, q = i & 15;
            int gr = rowBase + rr;
            uint4 u = make_uint4(0, 0, 0, 0);
            if (gr < N) u = *(const uint4*)(X + (size_t)gr * 128 + q * 8);
            uint arr[4] = {u.x, u.y, u.z, u.w};
            ushort* o = &xs[rr][q * 8];
#pragma unroll
            for (int j = 0; j < 4; ++j) {
                int c = q * 8 + j * 2;
                float lo = fmaxf(bflo(arr[j]) * scs[c] + shs[c], 0.f);
                float hi = fmaxf(bfhi(arr[j]) * scs[c + 1] + shs[c + 1], 0.f);
                o[j * 2]     = f2bf(lo);
                o[j * 2 + 1] = f2bf(hi);
            }
        }
    } else {
        const float* X = (const float*)Xv;
        for (int i = tid; i < BR * 32; i += 256) {
            int rr = i >> 5, c4 = i & 31;
            int gr = rowBase + rr;
            float4 v = make_float4(0.f, 0.f, 0.f, 0.f);
            if (gr < N) v = *(const float4*)(X + (size_t)gr * 128 + c4 * 4);
            ushort* o = &xs[rr][c4 * 4];
            o[0] = f2bf(v.x); o[1] = f2bf(v.y); o[2] = f2bf(v.z); o[3] = f2bf(v.w);
        }
    }
    for (int i = tid; i < M * 16; i += 256) {
        int rr = i >> 4, kc = (i & 15) * 8;
        *(uint4*)&ws[rr][kc] = *(const uint4*)(Wt + rr * 128 + kc);
    }
    __syncthreads();

    const int waveRow = (M == 128) ? 0 : (wv * 32);
    const int waveCol = (M == 128) ? (wv * 32) : 0;
    const int fr = lane & 15, quad = lane >> 4;

    f32x4 acc[RT][CT];
#pragma unroll
    for (int rt = 0; rt < RT; ++rt)
#pragma unroll
        for (int ct = 0; ct < CT; ++ct) acc[rt][ct] = (f32x4){0.f, 0.f, 0.f, 0.f};

#pragma unroll
    for (int ks = 0; ks < 4; ++ks) {
        const int kb = ks * 32 + quad * 8;
        bf16x8 a[RT], b[CT];
#pragma unroll
        for (int rt = 0; rt < RT; ++rt) a[rt] = *(const bf16x8*)&xs[waveRow + rt * 16 + fr][kb];
#pragma unroll
        for (int ct = 0; ct < CT; ++ct) b[ct] = *(const bf16x8*)&ws[waveCol + ct * 16 + fr][kb];
#pragma unroll
        for (int rt = 0; rt < RT; ++rt)
#pragma unroll
            for (int ct = 0; ct < CT; ++ct)
                acc[rt][ct] = __builtin_amdgcn_mfma_f32_16x16x32_bf16(a[rt], b[ct], acc[rt][ct], 0, 0, 0);
    }

#pragma unroll
    for (int rt = 0; rt < RT; ++rt)
#pragma unroll
        for (int ct = 0; ct < CT; ++ct)
#pragma unroll
            for (int rg = 0; rg < 4; ++rg) {
                int gr = rowBase + waveRow + rt * 16 + quad * 4 + rg;
                int gc = waveCol + ct * 16 + fr;
                if (gr < N) Y[(size_t)gr * M + gc] = f2bf(acc[rt][ct][rg]);
            }

    // fused el/er epilogue
    const float a0 = al[waveCol + fr],      a1 = al[waveCol + 16 + fr];
    const float g0 = ar[waveCol + fr],      g1 = ar[waveCol + 16 + fr];
    const int h = (M == 128) ? wv : 0;
#pragma unroll
    for (int rt = 0; rt < RT; ++rt)
#pragma unroll
        for (int rg = 0; rg < 4; ++rg) {
            float pe = acc[rt][0][rg] * a0 + acc[rt][1][rg] * a1;
            float pr = acc[rt][0][rg] * g0 + acc[rt][1][rg] * g1;
#pragma unroll
            for (int off = 1; off < 16; off <<= 1) {
                pe += __shfl_xor(pe, off);
                pr += __shfl_xor(pr, off);
            }
            int grow = rowBase + waveRow + rt * 16 + quad * 4 + rg;
            if (fr == 0 && grow < N) {
                el[grow * H + h] = pe;
                er[grow * H + h] = pr;
            }
        }
}

// ==================== gather H=4: one node/wave, bf16 out — NO atomics, NO LDS ====================
__global__ __launch_bounds__(256) void gat_gather4_kernel(
        const int* __restrict__ rowptr, const int* __restrict__ csr_src,
        const float* __restrict__ el, const float* __restrict__ er,
        const ushort* __restrict__ feat, const float* __restrict__ bias,
        ushort* __restrict__ xnext) {
    const int d = __builtin_amdgcn_readfirstlane(
        (int)((blockIdx.x * blockDim.x + threadIdx.x) >> 6));
    const int lane = threadIdx.x & 63;
    if (d >= NNODES) return;
    const int h   = lane >> 4;
    const int k   = lane & 15;
    const int grp = lane & 48;
    const int c0  = lane * 2;
    const int r0 = rowptr[d];
    const int deg = rowptr[d + 1] - r0;
    const float erh = er[d * 4 + h];
    float dnm = 0.f, ax = 0.f, ay = 0.f;

    for (int j0 = 0; j0 < deg; j0 += 16) {
        int eidx = j0 + k;
        int s_e = 0;
        float ex = 0.f;
        if (eidx < deg) {
            s_e = csr_src[r0 + eidx];
            float v = el[s_e * 4 + h] + erh;
            v = v > 0.f ? v : NEG_SLOPE * v;
            ex = __expf(v);
        }
        dnm += ex;
        uint u[16];
#pragma unroll
        for (int jj = 0; jj < 16; ++jj) {
            int sj = __builtin_amdgcn_readlane(s_e, jj);
            u[jj] = *(const uint*)(feat + (size_t)sj * 128 + c0);
        }
#pragma unroll
        for (int jj = 0; jj < 16; ++jj) {
            float exj = __shfl(ex, grp + jj);
            ax = fmaf(exj, bflo(u[jj]), ax);
            ay = fmaf(exj, bfhi(u[jj]), ay);
        }
    }
#pragma unroll
    for (int off = 1; off < 16; off <<= 1) dnm += __shfl_xor(dnm, off);
    float inv = (dnm > 0.f) ? 1.f / dnm : 0.f;
    float vx = ax * inv + bias[c0];
    float vy = ay * inv + bias[c0 + 1];
    uint pk = ((uint)f2bf(vy) << 16) | (uint)f2bf(vx);
    *(uint*)(xnext + (size_t)d * 128 + c0) = pk;
}

// ---- BN stats + FUSED finalize (last-block-done; 200 blocks so counter cost is tiny) ----
// NO per-block __threadfence: st_dev/atomicAdd complete at the coherence point and
// __syncthreads drains vmcnt before the counter bump. (Round-2 lesson: per-block
// agent fences = L2 invalidate storm; 12500 of them cost 240 µs in gather1.)
__global__ __launch_bounds__(256) void bn_stats_kernel(
        const ushort* __restrict__ X, float* __restrict__ psum, float* __restrict__ psumsq,
        const float* __restrict__ g, const float* __restrict__ beta,
        float* __restrict__ scale, float* __restrict__ shift, int* __restrict__ counter) {
    const uint* X32 = (const uint*)X;          // [N][64] packed col pairs
    int uc = threadIdx.x & 63;                 // uint col (cols 2uc, 2uc+1)
    int rq = threadIdx.x >> 6;                 // row quarter
    int r0 = blockIdx.x * BN_RPB;
    float s0 = 0.f, s1 = 0.f, ss0 = 0.f, ss1 = 0.f;
    for (int r = r0 + rq; r < r0 + BN_RPB; r += 4) {
        uint u = X32[(size_t)r * 64 + uc];
        float lo = bflo(u), hi = bfhi(u);
        s0 += lo; ss0 += lo * lo;
        s1 += hi; ss1 += hi * hi;
    }
    __shared__ float red[4][256], redsq[4][256];
    red[rq][uc * 2] = s0;      red[rq][uc * 2 + 1] = s1;
    redsq[rq][uc * 2] = ss0;   redsq[rq][uc * 2 + 1] = ss1;
    __syncthreads();
    int t = threadIdx.x;
    if (t < 128) {
        st_dev(&psum[blockIdx.x * 128 + t], red[0][t] + red[1][t] + red[2][t] + red[3][t]);
    } else {
        int c = t - 128;
        st_dev(&psumsq[blockIdx.x * 128 + c], redsq[0][c] + redsq[1][c] + redsq[2][c] + redsq[3][c]);
    }
    __syncthreads();   // drains vmcnt(0): all st_dev complete before counter bump
    __shared__ int isLast;
    if (t == 0) isLast = (atomicAdd(counter, 1) == (int)gridDim.x - 1);
    __syncthreads();
    if (!isLast) return;
    __threadfence();   // single acquire fence, last block only
    if (t < 128) {
        float s = 0.f, ss = 0.f;
        for (int b = 0; b < BN_NB; ++b) {
            s += ld_dev(&psum[b * 128 + t]);
            ss += ld_dev(&psumsq[b * 128 + t]);
        }
        const float inv = 1.f / NNODES;
        float mu = s * inv;
        float var = ss * inv - mu * mu;
        float sc = g[t] * rsqrtf(var + BN_EPS);
        scale[t] = sc;
        shift[t] = beta[t] - mu * sc;
    }
}

// ==================== gather H=1 with fused graph pooling (UNFUSED classifier) ====================
__global__ __launch_bounds__(256) void gat_gather1_kernel(
        const int* __restrict__ rowptr, const int* __restrict__ csr_src,
        const float* __restrict__ el, const float* __restrict__ er,
        const ushort* __restrict__ feat, const float* __restrict__ bias,
        const int* __restrict__ gid, float* __restrict__ pooled) {
    const int d = __builtin_amdgcn_readfirstlane(
        (int)((blockIdx.x * blockDim.x + threadIdx.x) >> 6));
    int lane = threadIdx.x & 63;
    if (d >= NNODES) return;
    const int r0 = rowptr[d];
    const int deg = rowptr[d + 1] - r0;
    const int half = lane >> 5;
    const int c    = lane & 31;
    const float erh = er[d];
    float dnm = 0.f, acc = 0.f;

    for (int j0 = 0; j0 < deg; j0 += 32) {
        int eidx = j0 + (lane & 31);
        int s_e = 0;
        float ex = 0.f;
        if (eidx < deg) {
            s_e = csr_src[r0 + eidx];
            float v = el[s_e] + erh;
            v = v > 0.f ? v : NEG_SLOPE * v;
            ex = __expf(v);
        }
        dnm += ex;
        ushort u[16];
#pragma unroll
        for (int jj = 0; jj < 16; ++jj) {
            int sj = __shfl(s_e, 2 * jj + half);
            u[jj] = feat[(size_t)sj * 32 + c];
        }
#pragma unroll
        for (int jj = 0; jj < 16; ++jj) {
            float exj = __shfl(ex, 2 * jj + half);
            acc = fmaf(exj, bf2f(u[jj]), acc);
        }
    }
#pragma unroll
    for (int off = 1; off < 32; off <<= 1) dnm += __shfl_xor(dnm, off);
    acc += __shfl_down(acc, 32);
    if (half == 0) {
        float inv = (dnm > 0.f) ? 1.f / dnm : 0.f;
        atomicAdd(&pooled[gid[d] * 32 + c], acc * inv + bias[c]);
    }
}

// ---- classifier (separate tiny launch — fusing it cost 240 µs, see round 2) ----
__global__ void classify_kernel(const float* __restrict__ pooled, const float* __restrict__ Wc,
                                const float* __restrict__ bc, float* __restrict__ out) {
    int t = blockIdx.x * blockDim.x + threadIdx.x;
    if (t >= NGRAPHS * 10) return;
    int gIdx = t / 10, j = t % 10;
    float s = bc[j];
#pragma unroll
    for (int c = 0; c < 32; ++c) s += pooled[gIdx * 32 + c] * Wc[c * 10 + j];
    out[t] = s;
}

extern "C" void kernel_launch(void* const* d_in, const int* in_sizes, int n_in,
                              void* d_out, int out_size, void* d_ws, size_t ws_size,
                              hipStream_t stream) {
    const float* x     = (const float*)d_in[0];
    const int*   esrc  = (const int*)d_in[1];
    const int*   edst  = (const int*)d_in[2];
    const int*   gid   = (const int*)d_in[3];
    const float* W0    = (const float*)d_in[4];
    const float* al0   = (const float*)d_in[5];
    const float* ar0   = (const float*)d_in[6];
    const float* b0    = (const float*)d_in[7];
    const float* W1    = (const float*)d_in[8];
    const float* al1   = (const float*)d_in[9];
    const float* ar1   = (const float*)d_in[10];
    const float* b1    = (const float*)d_in[11];
    const float* W2    = (const float*)d_in[12];
    const float* al2   = (const float*)d_in[13];
    const float* ar2   = (const float*)d_in[14];
    const float* b2    = (const float*)d_in[15];
    const float* g0    = (const float*)d_in[16];
    const float* beta0 = (const float*)d_in[17];
    const float* g1    = (const float*)d_in[18];
    const float* beta1 = (const float*)d_in[19];
    const float* Wc    = (const float*)d_in[20];
    const float* bc    = (const float*)d_in[21];

    // ---- workspace layout: one contiguous zero-init region first ----
    int*   counters = (int*)d_ws;                             // [8]: 0=bn0 1=bn1
    int*   rhist    = counters + 8;                           // [196]
    int*   rcursor  = rhist + NRANGE;                         // [196]
    float* pooled   = (float*)(rcursor + NRANGE);             // [500*32]
    // zero region ends here: (8+196+196+16000)*4 bytes
    float* psum     = pooled + NGRAPHS * 32;                  // [200*128]
    float* psumsq   = psum + BN_NB * 128;                     // [200*128]
    float* scale0   = psumsq + BN_NB * 128;                   // [128]
    float* shift0   = scale0 + 128;
    float* scale1   = shift0 + 128;
    float* shift1   = scale1 + 128;
    int*   rowptr   = (int*)(shift1 + 128);                   // [N+1]
    int*   csr_src  = rowptr + NNODES + 1;                    // [E]
    uint*  bucket   = (uint*)(csr_src + NEDGES);              // [E]
    size_t ofs = (size_t)((int*)(bucket + NEDGES) - (int*)d_ws);
    ofs = (ofs + 3) & ~(size_t)3;                             // 16B alignment
    ushort* featbf = (ushort*)((int*)d_ws + ofs);             // [N,128] bf16 GEMM out
    ushort* xnext  = featbf + (size_t)NNODES * 128;           // [N,128] bf16 gather out / GEMM in
    float*  el     = (float*)(xnext + (size_t)NNODES * 128);  // [N,4]
    float*  er     = el + (size_t)NNODES * 4;                 // [N,4]
    ushort* Wt0    = (ushort*)(er + (size_t)NNODES * 4);      // [128,128]
    ushort* Wt1    = Wt0 + 128 * 128;                         // [128,128]
    ushort* Wt2    = Wt1 + 128 * 128;                         // [32,128]

    const int T = 256;
    float* out = (float*)d_out;

    // ---- single zero-init (counters + rhist + rcursor + pooled) ----
    hipMemsetAsync(counters, 0, (size_t)(8 + NRANGE + NRANGE + NGRAPHS * 32) * 4, stream);
    prep_hist_kernel<<<RH_NB, T, 0, stream>>>(W0, W1, W2, Wt0, Wt1, Wt2, edst, rhist, rowptr);

    // ---- bucketed CSR build (scan folded into reorder/range_csr) ----
    reorder_kernel<<<RH_NB, T, 0, stream>>>(esrc, edst, rhist, rcursor, bucket);
    range_csr_kernel<<<NRANGE, T, 0, stream>>>(rhist, bucket, rowptr, csr_src);

    const int GATHER_BLOCKS  = (NNODES * 64) / T;             // exact: 12500
    const int GEMM128_BLOCKS = (NNODES + 63) / 64;
    const int GEMM32_BLOCKS  = (NNODES + 127) / 128;

    // ================= Layer 0 =================
    gemm_mfma_kernel<128, false><<<GEMM128_BLOCKS, T, 0, stream>>>(
        x, Wt0, nullptr, nullptr, al0, ar0, featbf, el, er, NNODES);
    gat_gather4_kernel<<<GATHER_BLOCKS, T, 0, stream>>>(rowptr, csr_src, el, er, featbf, b0, xnext);
    bn_stats_kernel<<<BN_NB, T, 0, stream>>>(xnext, psum, psumsq, g0, beta0, scale0, shift0,
                                             &counters[0]);

    // ================= Layer 1 =================
    gemm_mfma_kernel<128, true><<<GEMM128_BLOCKS, T, 0, stream>>>(
        xnext, Wt1, scale0, shift0, al1, ar1, featbf, el, er, NNODES);
    gat_gather4_kernel<<<GATHER_BLOCKS, T, 0, stream>>>(rowptr, csr_src, el, er, featbf, b1, xnext);
    bn_stats_kernel<<<BN_NB, T, 0, stream>>>(xnext, psum, psumsq, g1, beta1, scale1, shift1,
                                             &counters[1]);

    // ================= Layer 2 (H=1, D=32) =================
    gemm_mfma_kernel<32, true><<<GEMM32_BLOCKS, T, 0, stream>>>(
        xnext, Wt2, scale1, shift1, al2, ar2, featbf, el, er, NNODES);
    gat_gather1_kernel<<<GATHER_BLOCKS, T, 0, stream>>>(rowptr, csr_src, el, er, featbf, b2,
                                                        gid, pooled);

    // ================= Classify =================
    classify_kernel<<<(NGRAPHS * 10 + T - 1) / T, T, 0, stream>>>(pooled, Wc, bc, out);
}

// Round 4
// 355.961 us; speedup vs baseline: 1.7054x; 1.0067x over previous
//
#include <hip/hip_runtime.h>
#include <math.h>

#define NNODES 50000
#define NEDGES 800000
#define NGRAPHS 500
#define NEG_SLOPE 0.2f
#define BN_EPS 1e-5f
#define NRANGE 196            // ceil(50000/256) node ranges of 256
#define RH_EPB 2048           // edges per block in range hist/reorder (391 blocks)
#define RH_NB ((NEDGES + RH_EPB - 1) / RH_EPB)
#define MAXRE 5120            // LDS stage capacity per range
#define BN_NB 400
#define BN_RPB 125

typedef unsigned int uint;
typedef unsigned short ushort;
typedef __attribute__((ext_vector_type(8))) short bf16x8;
typedef __attribute__((ext_vector_type(4))) float f32x4;

// ---- bf16 helpers (storage-only bf16; math fp32 / MFMA fp32-acc) ----
__device__ __forceinline__ float bf2f(ushort u) { return __uint_as_float(((uint)u) << 16); }
__device__ __forceinline__ float bflo(uint u)   { return __uint_as_float(u << 16); }
__device__ __forceinline__ float bfhi(uint u)   { return __uint_as_float(u & 0xffff0000u); }
__device__ __forceinline__ ushort f2bf(float f) {
    uint u = __float_as_uint(f);
    u = (u + 0x7fffu + ((u >> 16) & 1u)) >> 16;   // RNE
    return (ushort)u;
}

// agent-scope (device) coherent load/store
__device__ __forceinline__ float ld_dev(const float* p) {
    return __hip_atomic_load(p, __ATOMIC_RELAXED, __HIP_MEMORY_SCOPE_AGENT);
}
__device__ __forceinline__ void st_dev(float* p, float v) {
    __hip_atomic_store(p, v, __ATOMIC_RELAXED, __HIP_MEMORY_SCOPE_AGENT);
}

// ---- prep (weight convert/transpose) FUSED with range histogram ----
__global__ __launch_bounds__(256) void prep_hist_kernel(
        const float* __restrict__ W0, const float* __restrict__ W1,
        const float* __restrict__ W2, ushort* __restrict__ Wt0,
        ushort* __restrict__ Wt1, ushort* __restrict__ Wt2,
        const int* __restrict__ dst, int* __restrict__ rhist,
        int* __restrict__ rowptr) {
    int t = blockIdx.x * 256 + threadIdx.x;
    if (t == 0) rowptr[NNODES] = NEDGES;
    if (t < 16384) {                       // W0 [128][128]
        int k = t >> 7, m = t & 127;
        Wt0[m * 128 + k] = f2bf(W0[t]);
    } else if (t < 32768) {                // W1 [128][128]
        int i = t - 16384;
        int k = i >> 7, m = i & 127;
        Wt1[m * 128 + k] = f2bf(W1[i]);
    } else if (t < 36864) {                // W2 [128][32]
        int i = t - 32768;
        int k = i >> 5, m = i & 31;
        Wt2[m * 128 + k] = f2bf(W2[i]);
    }
    __shared__ int cnt[NRANGE];
    for (int i = threadIdx.x; i < NRANGE; i += 256) cnt[i] = 0;
    __syncthreads();
    int base = blockIdx.x * RH_EPB;
    int end = base + RH_EPB; if (end > NEDGES) end = NEDGES;
    for (int i = base + threadIdx.x; i < end; i += 256) atomicAdd(&cnt[dst[i] >> 8], 1);
    __syncthreads();
    for (int i = threadIdx.x; i < NRANGE; i += 256)
        if (cnt[i]) atomicAdd(&rhist[i], cnt[i]);
}

// ==================== bucketed CSR build (scan fused redundantly per block) ====================
__global__ __launch_bounds__(256) void reorder_kernel(
        const int* __restrict__ src, const int* __restrict__ dst,
        const int* __restrict__ rhist, int* __restrict__ rcursor,
        uint* __restrict__ bucket) {
    __shared__ int cnt[NRANGE];
    __shared__ int bofs[NRANGE];
    __shared__ int rb[256];            // inclusive scan of rhist
    const int t = threadIdx.x;
    rb[t] = (t < NRANGE) ? rhist[t] : 0;
    if (t < NRANGE) cnt[t] = 0;
    __syncthreads();
    for (int off = 1; off < 256; off <<= 1) {
        int u = (t >= off) ? rb[t - off] : 0;
        __syncthreads();
        rb[t] += u;
        __syncthreads();
    }
    int base = blockIdx.x * RH_EPB;
    int end = base + RH_EPB; if (end > NEDGES) end = NEDGES;
    for (int i = base + t; i < end; i += 256) atomicAdd(&cnt[dst[i] >> 8], 1);
    __syncthreads();
    for (int i = t; i < NRANGE; i += 256) {
        int c = cnt[i];
        int ex = (i == 0) ? 0 : rb[i - 1];           // exclusive range base
        bofs[i] = c ? (ex + atomicAdd(&rcursor[i], c)) : 0;
    }
    __syncthreads();
    for (int i = t; i < NRANGE; i += 256) cnt[i] = 0;
    __syncthreads();
    for (int i = base + t; i < end; i += 256) {
        int d = dst[i], r = d >> 8;
        int loc = atomicAdd(&cnt[r], 1);
        bucket[bofs[r] + loc] = (uint)src[i] | ((uint)(d & 255) << 16);
    }
}

__global__ __launch_bounds__(256) void range_csr_kernel(const int* __restrict__ rhist,
                                                        const uint* __restrict__ bucket,
                                                        int* __restrict__ rowptr,
                                                        int* __restrict__ csr_src) {
    __shared__ uint ebuf[MAXRE];
    __shared__ int deg[256], excl[256], cur[256];
    __shared__ int rb[256];
    const int r = blockIdx.x;
    const int t = threadIdx.x;
    rb[t] = (t < NRANGE) ? rhist[t] : 0;
    __syncthreads();
    for (int off = 1; off < 256; off <<= 1) {
        int u = (t >= off) ? rb[t - off] : 0;
        __syncthreads();
        rb[t] += u;
        __syncthreads();
    }
    const int b0 = (r == 0) ? 0 : rb[r - 1];
    const int cnt = rb[r] - b0;
    deg[t] = 0; cur[t] = 0;
    __syncthreads();
    for (int i = t; i < cnt; i += 256) {
        uint e = bucket[b0 + i];
        ebuf[i] = e;
        atomicAdd(&deg[e >> 16], 1);
    }
    __syncthreads();
    excl[t] = deg[t];
    __syncthreads();
    for (int off = 1; off < 256; off <<= 1) {
        int u = (t >= off) ? excl[t - off] : 0;
        __syncthreads();
        excl[t] += u;
        __syncthreads();
    }
    int myExcl = (t == 0) ? 0 : excl[t - 1];
    __syncthreads();
    excl[t] = myExcl;
    __syncthreads();
    int node = r * 256 + t;
    if (node < NNODES) rowptr[node] = b0 + myExcl;
    for (int i = t; i < cnt; i += 256) {
        uint e = ebuf[i];
        int dl = e >> 16;
        int loc = atomicAdd(&cur[dl], 1);
        csr_src[b0 + excl[dl] + loc] = (int)(e & 0xffffu);
    }
}

// ==================== MFMA bf16 GEMM, fused BN/ReLU input + el/er epilogue ====================
// Changes this round:
//  - B fragments read straight from L2-resident Wt (no 32KB LDS staging) -> LDS/block
//    drops 53KB -> ~18KB: higher occupancy for the latency-heavy staging phase.
//  - Epilogue stores via LDS transpose (reusing xs after a sync): 16B coalesced row
//    stores instead of 32x scattered 2B stores per thread.
template <int M, bool HASBN>
__global__ __launch_bounds__(256) void gemm_mfma_kernel(
        const void* __restrict__ Xv, const ushort* __restrict__ Wt,
        const float* __restrict__ scale, const float* __restrict__ shift,
        const float* __restrict__ al, const float* __restrict__ ar,
        ushort* __restrict__ Y, float* __restrict__ el, float* __restrict__ er, int N) {
    constexpr int H   = M / 32;
    constexpr int BR  = (M == 128) ? 64 : 128;
    constexpr int RT  = (M == 128) ? 4 : 2;
    constexpr int CT  = 2;
    constexpr int LDK = 136;
    __shared__ ushort xs[BR][LDK];
    __shared__ float scs[128], shs[128];

    const int tid = threadIdx.x, wv = tid >> 6, lane = tid & 63;
    const int rowBase = blockIdx.x * BR;

    if (HASBN) {
        if (tid < 128) {
            scs[tid] = scale[tid];
            shs[tid] = shift[tid];
        }
        __syncthreads();
    }

    if (HASBN) {
        const ushort* X = (const ushort*)Xv;
        for (int i = tid; i < BR * 16; i += 256) {
            int rr = i >> 4, q = i & 15;
            int gr = rowBase + rr;
            uint4 u = make_uint4(0, 0, 0, 0);
            if (gr < N) u = *(const uint4*)(X + (size_t)gr * 128 + q * 8);
            uint arr[4] = {u.x, u.y, u.z, u.w};
            ushort* o = &xs[rr][q * 8];
#pragma unroll
            for (int j = 0; j < 4; ++j) {
                int c = q * 8 + j * 2;
                float lo = fmaxf(bflo(arr[j]) * scs[c] + shs[c], 0.f);
                float hi = fmaxf(bfhi(arr[j]) * scs[c + 1] + shs[c + 1], 0.f);
                o[j * 2]     = f2bf(lo);
                o[j * 2 + 1] = f2bf(hi);
            }
        }
    } else {
        const float* X = (const float*)Xv;
        for (int i = tid; i < BR * 32; i += 256) {
            int rr = i >> 5, c4 = i & 31;
            int gr = rowBase + rr;
            float4 v = make_float4(0.f, 0.f, 0.f, 0.f);
            if (gr < N) v = *(const float4*)(X + (size_t)gr * 128 + c4 * 4);
            ushort* o = &xs[rr][c4 * 4];
            o[0] = f2bf(v.x); o[1] = f2bf(v.y); o[2] = f2bf(v.z); o[3] = f2bf(v.w);
        }
    }
    __syncthreads();

    const int waveRow = (M == 128) ? 0 : (wv * 32);
    const int waveCol = (M == 128) ? (wv * 32) : 0;
    const int fr = lane & 15, quad = lane >> 4;

    f32x4 acc[RT][CT];
#pragma unroll
    for (int rt = 0; rt < RT; ++rt)
#pragma unroll
        for (int ct = 0; ct < CT; ++ct) acc[rt][ct] = (f32x4){0.f, 0.f, 0.f, 0.f};

#pragma unroll
    for (int ks = 0; ks < 4; ++ks) {
        const int kb = ks * 32 + quad * 8;
        bf16x8 a[RT], b[CT];
#pragma unroll
        for (int rt = 0; rt < RT; ++rt) a[rt] = *(const bf16x8*)&xs[waveRow + rt * 16 + fr][kb];
#pragma unroll
        for (int ct = 0; ct < CT; ++ct)
            b[ct] = *(const bf16x8*)(Wt + (size_t)(waveCol + ct * 16 + fr) * 128 + kb);
#pragma unroll
        for (int rt = 0; rt < RT; ++rt)
#pragma unroll
            for (int ct = 0; ct < CT; ++ct)
                acc[rt][ct] = __builtin_amdgcn_mfma_f32_16x16x32_bf16(a[rt], b[ct], acc[rt][ct], 0, 0, 0);
    }

    // fused el/er epilogue (register-only + tiny global writes; before xs reuse)
    const float a0 = al[waveCol + fr],      a1 = al[waveCol + 16 + fr];
    const float g0 = ar[waveCol + fr],      g1 = ar[waveCol + 16 + fr];
    const int h = (M == 128) ? wv : 0;
#pragma unroll
    for (int rt = 0; rt < RT; ++rt)
#pragma unroll
        for (int rg = 0; rg < 4; ++rg) {
            float pe = acc[rt][0][rg] * a0 + acc[rt][1][rg] * a1;
            float pr = acc[rt][0][rg] * g0 + acc[rt][1][rg] * g1;
#pragma unroll
            for (int off = 1; off < 16; off <<= 1) {
                pe += __shfl_xor(pe, off);
                pr += __shfl_xor(pr, off);
            }
            int grow = rowBase + waveRow + rt * 16 + quad * 4 + rg;
            if (fr == 0 && grow < N) {
                el[grow * H + h] = pe;
                er[grow * H + h] = pr;
            }
        }

    // ---- coalesced Y store via LDS transpose (reuse xs) ----
    __syncthreads();   // all fragment reads of xs complete
#pragma unroll
    for (int rt = 0; rt < RT; ++rt)
#pragma unroll
        for (int ct = 0; ct < CT; ++ct)
#pragma unroll
            for (int rg = 0; rg < 4; ++rg) {
                int lr = waveRow + rt * 16 + quad * 4 + rg;
                int lc = waveCol + ct * 16 + fr;
                xs[lr][lc] = f2bf(acc[rt][ct][rg]);
            }
    __syncthreads();
    if (M == 128) {
        int row = tid >> 2, seg = tid & 3;
        int gr = rowBase + row;
        if (gr < N) {
#pragma unroll
            for (int q = 0; q < 4; ++q) {
                int col = (seg * 4 + q) * 8;
                *(uint4*)(Y + (size_t)gr * 128 + col) = *(const uint4*)&xs[row][col];
            }
        }
    } else {
        int row = tid >> 1, hf = tid & 1;
        int gr = rowBase + row;
        if (gr < N) {
#pragma unroll
            for (int q = 0; q < 2; ++q) {
                int col = (hf * 2 + q) * 8;
                *(uint4*)(Y + (size_t)gr * 32 + col) = *(const uint4*)&xs[row][col];
            }
        }
    }
}

// ==================== gather H=4: one node/wave, software-pipelined chunks ====================
// Next chunk's csr_src load issues before the current feat phase; next exp computes
// under the feat loads' vmcnt shadow.
__global__ __launch_bounds__(256) void gat_gather4_kernel(
        const int* __restrict__ rowptr, const int* __restrict__ csr_src,
        const float* __restrict__ el, const float* __restrict__ er,
        const ushort* __restrict__ feat, const float* __restrict__ bias,
        ushort* __restrict__ xnext) {
    const int d = __builtin_amdgcn_readfirstlane(
        (int)((blockIdx.x * blockDim.x + threadIdx.x) >> 6));
    const int lane = threadIdx.x & 63;
    if (d >= NNODES) return;
    const int h   = lane >> 4;
    const int k   = lane & 15;
    const int grp = lane & 48;
    const int c0  = lane * 2;
    const int r0 = rowptr[d];
    const int deg = rowptr[d + 1] - r0;
    const float erh = er[d * 4 + h];
    float dnm = 0.f, ax = 0.f, ay = 0.f;

    // prologue: chunk 0 score
    int s_c = 0; float ex_c = 0.f;
    if (k < deg) {
        s_c = csr_src[r0 + k];
        float v = el[s_c * 4 + h] + erh;
        v = v > 0.f ? v : NEG_SLOPE * v;
        ex_c = __expf(v);
    }
    for (int j0 = 0; j0 < deg; j0 += 16) {
        const int nidx = j0 + 16 + k;
        int s_n = 0;
        if (nidx < deg) s_n = csr_src[r0 + nidx];       // prefetch next chunk's src ids
        dnm += ex_c;
        uint u[16];
#pragma unroll
        for (int jj = 0; jj < 16; ++jj) {
            int sj = __builtin_amdgcn_readlane(s_c, jj);
            u[jj] = *(const uint*)(feat + (size_t)sj * 128 + c0);
        }
        float ex_n = 0.f;
        if (nidx < deg) {                                // overlaps feat loads in flight
            float v = el[s_n * 4 + h] + erh;
            v = v > 0.f ? v : NEG_SLOPE * v;
            ex_n = __expf(v);
        }
#pragma unroll
        for (int jj = 0; jj < 16; ++jj) {
            float exj = __shfl(ex_c, grp + jj);
            ax = fmaf(exj, bflo(u[jj]), ax);
            ay = fmaf(exj, bfhi(u[jj]), ay);
        }
        s_c = s_n; ex_c = ex_n;
    }
#pragma unroll
    for (int off = 1; off < 16; off <<= 1) dnm += __shfl_xor(dnm, off);
    float inv = (dnm > 0.f) ? 1.f / dnm : 0.f;
    float vx = ax * inv + bias[c0];
    float vy = ay * inv + bias[c0 + 1];
    uint pk = ((uint)f2bf(vy) << 16) | (uint)f2bf(vx);
    *(uint*)(xnext + (size_t)d * 128 + c0) = pk;
}

// ---- BN stats + FUSED finalize (last-block-done; 400 blocks for occupancy) ----
// NO per-block __threadfence (round-2 lesson: per-block agent fences = L2
// invalidate storm). st_dev completes at coherence point; __syncthreads drains vmcnt.
__global__ __launch_bounds__(256) void bn_stats_kernel(
        const ushort* __restrict__ X, float* __restrict__ psum, float* __restrict__ psumsq,
        const float* __restrict__ g, const float* __restrict__ beta,
        float* __restrict__ scale, float* __restrict__ shift, int* __restrict__ counter) {
    const uint* X32 = (const uint*)X;          // [N][64] packed col pairs
    int uc = threadIdx.x & 63;                 // uint col (cols 2uc, 2uc+1)
    int rq = threadIdx.x >> 6;                 // row quarter
    int r0 = blockIdx.x * BN_RPB;
    float s0 = 0.f, s1 = 0.f, ss0 = 0.f, ss1 = 0.f;
    for (int r = r0 + rq; r < r0 + BN_RPB; r += 4) {
        uint u = X32[(size_t)r * 64 + uc];
        float lo = bflo(u), hi = bfhi(u);
        s0 += lo; ss0 += lo * lo;
        s1 += hi; ss1 += hi * hi;
    }
    __shared__ float red[4][256], redsq[4][256];
    red[rq][uc * 2] = s0;      red[rq][uc * 2 + 1] = s1;
    redsq[rq][uc * 2] = ss0;   redsq[rq][uc * 2 + 1] = ss1;
    __syncthreads();
    int t = threadIdx.x;
    if (t < 128) {
        st_dev(&psum[blockIdx.x * 128 + t], red[0][t] + red[1][t] + red[2][t] + red[3][t]);
    } else {
        int c = t - 128;
        st_dev(&psumsq[blockIdx.x * 128 + c], redsq[0][c] + redsq[1][c] + redsq[2][c] + redsq[3][c]);
    }
    __syncthreads();   // drains vmcnt(0): all st_dev complete before counter bump
    __shared__ int isLast;
    if (t == 0) isLast = (atomicAdd(counter, 1) == (int)gridDim.x - 1);
    __syncthreads();
    if (!isLast) return;
    __threadfence();   // single acquire fence, last block only
    if (t < 128) {
        float s = 0.f, ss = 0.f;
        for (int b = 0; b < BN_NB; ++b) {
            s += ld_dev(&psum[b * 128 + t]);
            ss += ld_dev(&psumsq[b * 128 + t]);
        }
        const float inv = 1.f / NNODES;
        float mu = s * inv;
        float var = ss * inv - mu * mu;
        float sc = g[t] * rsqrtf(var + BN_EPS);
        scale[t] = sc;
        shift[t] = beta[t] - mu * sc;
    }
}

// ==================== gather H=1 with fused graph pooling ====================
__global__ __launch_bounds__(256) void gat_gather1_kernel(
        const int* __restrict__ rowptr, const int* __restrict__ csr_src,
        const float* __restrict__ el, const float* __restrict__ er,
        const ushort* __restrict__ feat, const float* __restrict__ bias,
        const int* __restrict__ gid, float* __restrict__ pooled) {
    const int d = __builtin_amdgcn_readfirstlane(
        (int)((blockIdx.x * blockDim.x + threadIdx.x) >> 6));
    int lane = threadIdx.x & 63;
    if (d >= NNODES) return;
    const int r0 = rowptr[d];
    const int deg = rowptr[d + 1] - r0;
    const int half = lane >> 5;
    const int c    = lane & 31;
    const float erh = er[d];
    float dnm = 0.f, acc = 0.f;

    for (int j0 = 0; j0 < deg; j0 += 32) {
        int eidx = j0 + (lane & 31);
        int s_e = 0;
        float ex = 0.f;
        if (eidx < deg) {
            s_e = csr_src[r0 + eidx];
            float v = el[s_e] + erh;
            v = v > 0.f ? v : NEG_SLOPE * v;
            ex = __expf(v);
        }
        dnm += ex;
        ushort u[16];
#pragma unroll
        for (int jj = 0; jj < 16; ++jj) {
            int sj = __shfl(s_e, 2 * jj + half);
            u[jj] = feat[(size_t)sj * 32 + c];
        }
#pragma unroll
        for (int jj = 0; jj < 16; ++jj) {
            float exj = __shfl(ex, 2 * jj + half);
            acc = fmaf(exj, bf2f(u[jj]), acc);
        }
    }
#pragma unroll
    for (int off = 1; off < 32; off <<= 1) dnm += __shfl_xor(dnm, off);
    acc += __shfl_down(acc, 32);
    if (half == 0) {
        float inv = (dnm > 0.f) ? 1.f / dnm : 0.f;
        atomicAdd(&pooled[gid[d] * 32 + c], acc * inv + bias[c]);
    }
}

// ---- classifier (separate tiny launch — fusing it cost 240 µs, see round 2) ----
__global__ void classify_kernel(const float* __restrict__ pooled, const float* __restrict__ Wc,
                                const float* __restrict__ bc, float* __restrict__ out) {
    int t = blockIdx.x * blockDim.x + threadIdx.x;
    if (t >= NGRAPHS * 10) return;
    int gIdx = t / 10, j = t % 10;
    float s = bc[j];
#pragma unroll
    for (int c = 0; c < 32; ++c) s += pooled[gIdx * 32 + c] * Wc[c * 10 + j];
    out[t] = s;
}

extern "C" void kernel_launch(void* const* d_in, const int* in_sizes, int n_in,
                              void* d_out, int out_size, void* d_ws, size_t ws_size,
                              hipStream_t stream) {
    const float* x     = (const float*)d_in[0];
    const int*   esrc  = (const int*)d_in[1];
    const int*   edst  = (const int*)d_in[2];
    const int*   gid   = (const int*)d_in[3];
    const float* W0    = (const float*)d_in[4];
    const float* al0   = (const float*)d_in[5];
    const float* ar0   = (const float*)d_in[6];
    const float* b0    = (const float*)d_in[7];
    const float* W1    = (const float*)d_in[8];
    const float* al1   = (const float*)d_in[9];
    const float* ar1   = (const float*)d_in[10];
    const float* b1    = (const float*)d_in[11];
    const float* W2    = (const float*)d_in[12];
    const float* al2   = (const float*)d_in[13];
    const float* ar2   = (const float*)d_in[14];
    const float* b2    = (const float*)d_in[15];
    const float* g0    = (const float*)d_in[16];
    const float* beta0 = (const float*)d_in[17];
    const float* g1    = (const float*)d_in[18];
    const float* beta1 = (const float*)d_in[19];
    const float* Wc    = (const float*)d_in[20];
    const float* bc    = (const float*)d_in[21];

    // ---- workspace layout: one contiguous zero-init region first ----
    int*   counters = (int*)d_ws;                             // [8]: 0=bn0 1=bn1
    int*   rhist    = counters + 8;                           // [196]
    int*   rcursor  = rhist + NRANGE;                         // [196]
    float* pooled   = (float*)(rcursor + NRANGE);             // [500*32]
    // zero region ends here: (8+196+196+16000)*4 bytes
    float* psum     = pooled + NGRAPHS * 32;                  // [400*128]
    float* psumsq   = psum + BN_NB * 128;                     // [400*128]
    float* scale0   = psumsq + BN_NB * 128;                   // [128]
    float* shift0   = scale0 + 128;
    float* scale1   = shift0 + 128;
    float* shift1   = scale1 + 128;
    int*   rowptr   = (int*)(shift1 + 128);                   // [N+1]
    int*   csr_src  = rowptr + NNODES + 1;                    // [E]
    uint*  bucket   = (uint*)(csr_src + NEDGES);              // [E]
    size_t ofs = (size_t)((int*)(bucket + NEDGES) - (int*)d_ws);
    ofs = (ofs + 3) & ~(size_t)3;                             // 16B alignment
    ushort* featbf = (ushort*)((int*)d_ws + ofs);             // [N,128] bf16 GEMM out
    ushort* xnext  = featbf + (size_t)NNODES * 128;           // [N,128] bf16 gather out / GEMM in
    float*  el     = (float*)(xnext + (size_t)NNODES * 128);  // [N,4]
    float*  er     = el + (size_t)NNODES * 4;                 // [N,4]
    ushort* Wt0    = (ushort*)(er + (size_t)NNODES * 4);      // [128,128]
    ushort* Wt1    = Wt0 + 128 * 128;                         // [128,128]
    ushort* Wt2    = Wt1 + 128 * 128;                         // [32,128]

    const int T = 256;
    float* out = (float*)d_out;

    // ---- single zero-init (counters + rhist + rcursor + pooled) ----
    hipMemsetAsync(counters, 0, (size_t)(8 + NRANGE + NRANGE + NGRAPHS * 32) * 4, stream);
    prep_hist_kernel<<<RH_NB, T, 0, stream>>>(W0, W1, W2, Wt0, Wt1, Wt2, edst, rhist, rowptr);

    // ---- bucketed CSR build (scan folded into reorder/range_csr) ----
    reorder_kernel<<<RH_NB, T, 0, stream>>>(esrc, edst, rhist, rcursor, bucket);
    range_csr_kernel<<<NRANGE, T, 0, stream>>>(rhist, bucket, rowptr, csr_src);

    const int GATHER_BLOCKS  = (NNODES * 64) / T;             // exact: 12500
    const int GEMM128_BLOCKS = (NNODES + 63) / 64;
    const int GEMM32_BLOCKS  = (NNODES + 127) / 128;

    // ================= Layer 0 =================
    gemm_mfma_kernel<128, false><<<GEMM128_BLOCKS, T, 0, stream>>>(
        x, Wt0, nullptr, nullptr, al0, ar0, featbf, el, er, NNODES);
    gat_gather4_kernel<<<GATHER_BLOCKS, T, 0, stream>>>(rowptr, csr_src, el, er, featbf, b0, xnext);
    bn_stats_kernel<<<BN_NB, T, 0, stream>>>(xnext, psum, psumsq, g0, beta0, scale0, shift0,
                                             &counters[0]);

    // ================= Layer 1 =================
    gemm_mfma_kernel<128, true><<<GEMM128_BLOCKS, T, 0, stream>>>(
        xnext, Wt1, scale0, shift0, al1, ar1, featbf, el, er, NNODES);
    gat_gather4_kernel<<<GATHER_BLOCKS, T, 0, stream>>>(rowptr, csr_src, el, er, featbf, b1, xnext);
    bn_stats_kernel<<<BN_NB, T, 0, stream>>>(xnext, psum, psumsq, g1, beta1, scale1, shift1,
                                             &counters[1]);

    // ================= Layer 2 (H=1, D=32) =================
    gemm_mfma_kernel<32, true><<<GEMM32_BLOCKS, T, 0, stream>>>(
        xnext, Wt2, scale1, shift1, al2, ar2, featbf, el, er, NNODES);
    gat_gather1_kernel<<<GATHER_BLOCKS, T, 0, stream>>>(rowptr, csr_src, el, er, featbf, b2,
                                                        gid, pooled);

    // ================= Classify =================
    classify_kernel<<<(NGRAPHS * 10 + T - 1) / T, T, 0, stream>>>(pooled, Wc, bc, out);
}